// Round 3
// baseline (57311.682 us; speedup 1.0000x reference)
//
#include <hip/hip_runtime.h>

// LSTMRecursiveModel: B=16, L=96, H=256, NL=2, O=32.
// 3168 sequential LSTM steps. Cooperative persistent kernel, 1 grid barrier per
// step (software-pipelined: phase p computes L0(step p) || L1(step p-1)).
//
// Round 2: 24 WGs x 1024 threads (was 96 x 256) -- same lane count, 4x fewer
// barrier participants. Contention-free flag barrier (per-WG padded flag +
// poll-all by wave 0 of every WG) replaces serialized atomic-RMW barrier.
// h streamed from global (L1-cached) instead of big register arrays to keep
// VGPR <= 128 (16 waves/CU must co-reside).
// Weights persistent in LDS (dynamic, 139264 B/WG):
//   WG 0..7   : layer0, 32 h-columns each (128 rows of Whh0)
//   WG 8..23  : layer1, 16 h-columns each (64 Wih1 rows + 64 Whh1 rows)
// Cell state c in registers (double precision) of the owning lane.

#define NWG 24
#define LASTP 3169   // phases p = 0..3169; L0 active p<=3167, L1 active 1<=p<=3168

__device__ __forceinline__ float sigm(float x) { return 1.0f / (1.0f + expf(-x)); }

// ws layout (floats):
//   h0buf : [2][16][256] at 0      (double-buffered by step parity)
//   h1buf : [2][16][256] at 8192
//   predbuf: [32][16]    at 16384
//   flags  : 24 uints, 64B-strided, at 17024 (..17408)
__global__ void init_kernel(float* __restrict__ out, float* __restrict__ ws) {
  int i = blockIdx.x * blockDim.x + threadIdx.x;
  if (i < 16 * 96) out[i] = 0.0f;
  for (int j = i; j < 17408; j += gridDim.x * blockDim.x) ws[j] = 0.0f;
}

extern "C" __global__ __launch_bounds__(1024, 1) void lstm_coop(
    const float* __restrict__ x_enc,
    const float* __restrict__ Wih0, const float* __restrict__ Whh0,
    const float* __restrict__ bih0, const float* __restrict__ bhh0,
    const float* __restrict__ Wih1, const float* __restrict__ Whh1,
    const float* __restrict__ bih1, const float* __restrict__ bhh1,
    const float* __restrict__ fc_w, const float* __restrict__ fc_b,
    float* __restrict__ out, float* __restrict__ ws) {
  const int w = blockIdx.x;
  const int tid = threadIdx.x;
  const int wave = tid >> 6, lane = tid & 63;
  const int b = lane & 15, q = lane >> 4;   // batch, k-segment (64 k each)

  float* h0buf = ws;
  float* h1buf = ws + 8192;
  float* predbuf = ws + 16384;
  unsigned* flags = (unsigned*)(ws + 17024);

  // 128 rows x (4 segs x 68 floats) : addr = R*272 + q*68 + j.
  // Bank of float4 base = (16R + 4q + 4jj) & 31 -> the 4 q-addresses per
  // wave-instruction hit disjoint banks; 16 same-address lanes broadcast.
  extern __shared__ float wlds[];   // 128 * 272 floats = 139264 B

  const bool isL0 = (w < 8);
  const int u = w - 8;

  // ---- stage weights into LDS ----
  for (int e = tid; e < 128 * 256; e += 1024) {
    int row = e >> 8;          // LDS row 0..127 (= wave*8 + r)
    int k = e & 255;
    int wv = row >> 3, r = row & 7;
    int dst = row * 272 + (k >> 6) * 68 + (k & 63);
    if (isL0) {
      int col = w * 32 + wv * 2 + (r >> 2), gate = r & 3;
      wlds[dst] = Whh0[(gate * 256 + col) * 256 + k];
    } else {
      int col = u * 16 + wv, gate = r & 3;
      const float* Wsrc = (r >= 4) ? Whh1 : Wih1;
      wlds[dst] = Wsrc[(gate * 256 + col) * 256 + k];
    }
  }

  // ---- per-lane constants ----
  float biasv[8], xw[8];
  if (isL0) {
#pragma unroll
    for (int r = 0; r < 8; ++r) {
      int col = w * 32 + wave * 2 + (r >> 2), gate = r & 3;
      int grow = gate * 256 + col;
      biasv[r] = bih0[grow] + bhh0[grow];
      xw[r] = Wih0[grow];   // Wih0 is (1024,1): scalar x-weight per gate row
    }
  } else {
#pragma unroll
    for (int g = 0; g < 4; ++g) {
      int col = u * 16 + wave;
      int grow = g * 256 + col;
      biasv[g] = bih1[grow] + bhh1[grow];
      xw[g] = 0.0f;
    }
#pragma unroll
    for (int g = 4; g < 8; ++g) { biasv[g] = 0.0f; xw[g] = 0.0f; }
  }
  __syncthreads();

  double c0a = 0.0, c0b = 0.0, c1 = 0.0;   // cell states (valid on q==0 lanes)
  const int colBaseL0 = w * 32 + wave * 2;  // L0 wave owns 2 columns
  const int colL1 = u * 16 + wave;          // L1 wave owns 1 column

  for (int p = 0; p <= LASTP; ++p) {
    if (isL0) {
      if (p <= 3167) {
        // ---- layer 0, step p: gates = x*wih0 + h0 @ Whh0^T + bias ----
        const float* hsrc = h0buf + ((p + 1) & 1) * 4096 + b * 256 + q * 64;
        float acc[8];
#pragma unroll
        for (int r = 0; r < 8; ++r) acc[r] = 0.0f;
        const int rbase = wave * 8 * 272 + q * 68;
#pragma unroll
        for (int jj = 0; jj < 16; ++jj) {
          float4 hv = *(const float4*)(hsrc + jj * 4);
#pragma unroll
          for (int r = 0; r < 8; ++r) {
            float4 wv = *(const float4*)&wlds[rbase + r * 272 + jj * 4];
            acc[r] += wv.x * hv.x + wv.y * hv.y + wv.z * hv.z + wv.w * hv.w;
          }
        }
#pragma unroll
        for (int r = 0; r < 8; ++r) {
          acc[r] += __shfl_xor(acc[r], 16);
          acc[r] += __shfl_xor(acc[r], 32);
        }
        if (q == 0) {
          float xv;
          {
            int s = p;
            if (s < 96) {
              xv = x_enc[b * 96 + s];
            } else {
              int sk = s - 96;
              int k = sk / 96;
              int t = sk - k * 96;
              xv = (t < 96 - k) ? x_enc[b * 96 + k + t] : predbuf[(t - 96 + k) * 16 + b];
            }
          }
          float hv0, hv1;
          {
            float gi = acc[0] + xv * xw[0] + biasv[0];
            float gf = acc[1] + xv * xw[1] + biasv[1];
            float gg = acc[2] + xv * xw[2] + biasv[2];
            float go = acc[3] + xv * xw[3] + biasv[3];
            double cn = (double)sigm(gf) * c0a + (double)(sigm(gi) * tanhf(gg));
            hv0 = sigm(go) * tanhf((float)cn);
            c0a = cn;
          }
          {
            float gi = acc[4] + xv * xw[4] + biasv[4];
            float gf = acc[5] + xv * xw[5] + biasv[5];
            float gg = acc[6] + xv * xw[6] + biasv[6];
            float go = acc[7] + xv * xw[7] + biasv[7];
            double cn = (double)sigm(gf) * c0b + (double)(sigm(gi) * tanhf(gg));
            hv1 = sigm(go) * tanhf((float)cn);
            c0b = cn;
          }
          *(float2*)(h0buf + (p & 1) * 4096 + b * 256 + colBaseL0) = make_float2(hv0, hv1);
        }
      }
      // ---- prediction (one phase after h1(s) lands; s=191+96*jp is odd) ----
      if (w == 0 && wave == 0 && p >= 193 && ((p - 193) % 96) == 0) {
        int jp = (p - 193) / 96;
        if (jp < 32) {
          const float* hsrc = h1buf + 4096 + b * 256 + q * 64;  // parity 1 always
          const float* fw = fc_w + q * 64;
          float acc = 0.0f;
#pragma unroll
          for (int jj = 0; jj < 16; ++jj) {
            float4 hv = *(const float4*)(hsrc + jj * 4);
            float4 wv = *(const float4*)(fw + jj * 4);
            acc += hv.x * wv.x + hv.y * wv.y + hv.z * wv.z + hv.w * wv.w;
          }
          acc += __shfl_xor(acc, 16);
          acc += __shfl_xor(acc, 32);
          if (q == 0) {
            float pv = acc + fc_b[0];
            predbuf[jp * 16 + b] = pv;
            out[b * 96 + jp] = pv;
          }
        }
      }
    } else {
      if (p >= 1 && p <= 3168) {
        // ---- layer 1, step s=p-1: gates = h0'(s) @ Wih1^T + h1(s-1) @ Whh1^T + bias ----
        const float* h0src = h0buf + ((p + 1) & 1) * 4096 + b * 256 + q * 64;
        const float* h1src = h1buf + (p & 1) * 4096 + b * 256 + q * 64;
        float acc[8];
#pragma unroll
        for (int r = 0; r < 8; ++r) acc[r] = 0.0f;
        const int rbase = wave * 8 * 272 + q * 68;
#pragma unroll
        for (int jj = 0; jj < 16; ++jj) {
          float4 h0v = *(const float4*)(h0src + jj * 4);
          float4 h1v = *(const float4*)(h1src + jj * 4);
#pragma unroll
          for (int r = 0; r < 4; ++r) {   // Wih1 rows (input = h0')
            float4 wv = *(const float4*)&wlds[rbase + r * 272 + jj * 4];
            acc[r] += wv.x * h0v.x + wv.y * h0v.y + wv.z * h0v.z + wv.w * h0v.w;
          }
#pragma unroll
          for (int r = 4; r < 8; ++r) {   // Whh1 rows (input = h1)
            float4 wv = *(const float4*)&wlds[rbase + r * 272 + jj * 4];
            acc[r] += wv.x * h1v.x + wv.y * h1v.y + wv.z * h1v.z + wv.w * h1v.w;
          }
        }
#pragma unroll
        for (int r = 0; r < 8; ++r) {
          acc[r] += __shfl_xor(acc[r], 16);
          acc[r] += __shfl_xor(acc[r], 32);
        }
        if (q == 0) {
          float gi = acc[0] + acc[4] + biasv[0];
          float gf = acc[1] + acc[5] + biasv[1];
          float gg = acc[2] + acc[6] + biasv[2];
          float go = acc[3] + acc[7] + biasv[3];
          double cn = (double)sigm(gf) * c1 + (double)(sigm(gi) * tanhf(gg));
          float hn = sigm(go) * tanhf((float)cn);
          c1 = cn;
          h1buf[((p + 1) & 1) * 4096 + b * 256 + colL1] = hn;
        }
      }
    }

    // ---- grid barrier: per-WG flag store + poll-all (no contention) ----
    __syncthreads();   // all waves' stores drained to L2 (vmcnt) before signal
    if (tid == 0) {
      // release at agent scope: writes back dirty L2 so remote XCDs see h
      __hip_atomic_store(&flags[w * 16], (unsigned)(p + 1), __ATOMIC_RELEASE,
                         __HIP_MEMORY_SCOPE_AGENT);
    }
    if (wave == 0) {
      const bool active = lane < NWG;
      unsigned* myf = flags + (active ? lane : 0) * 16;
      const unsigned tgt = (unsigned)(p + 1);
      while (!__all(!active ||
                    __hip_atomic_load(myf, __ATOMIC_RELAXED,
                                      __HIP_MEMORY_SCOPE_AGENT) >= tgt)) {
      }
      __threadfence();   // acquire: invalidate stale cached h before next phase
    }
    __syncthreads();
  }
}

extern "C" void kernel_launch(void* const* d_in, const int* in_sizes, int n_in,
                              void* d_out, int out_size, void* d_ws, size_t ws_size,
                              hipStream_t stream) {
  const float* x_enc = (const float*)d_in[0];
  const float* Wih0 = (const float*)d_in[4];
  const float* Whh0 = (const float*)d_in[5];
  const float* bih0 = (const float*)d_in[6];
  const float* bhh0 = (const float*)d_in[7];
  const float* Wih1 = (const float*)d_in[8];
  const float* Whh1 = (const float*)d_in[9];
  const float* bih1 = (const float*)d_in[10];
  const float* bhh1 = (const float*)d_in[11];
  const float* fc_w = (const float*)d_in[12];
  const float* fc_b = (const float*)d_in[13];
  float* out = (float*)d_out;
  float* ws = (float*)d_ws;

  hipLaunchKernelGGL(init_kernel, dim3(8), dim3(256), 0, stream, out, ws);

  const int ldsBytes = 128 * 272 * 4;   // 139264
  static int attrSet = 0;
  if (!attrSet) {
    (void)hipFuncSetAttribute((const void*)lstm_coop,
                              hipFuncAttributeMaxDynamicSharedMemorySize, ldsBytes);
    attrSet = 1;
  }

  void* args[] = {&x_enc, &Wih0, &Whh0, &bih0, &bhh0, &Wih1, &Whh1, &bih1, &bhh1,
                  &fc_w, &fc_b, &out, &ws};
  (void)hipLaunchCooperativeKernel((void*)lstm_coop, dim3(NWG), dim3(1024), args,
                                   (unsigned)ldsBytes, stream);
}